// Round 1
// baseline (1026.465 us; speedup 1.0000x reference)
//
#include <hip/hip_runtime.h>
#include <cstddef>
#include <cstdint>

#define NNODES 20000
#define SDIM 256

// ---------------- nsum: sum over M=2 ----------------
__global__ void nsum_kernel(const float* __restrict__ nodes, float* __restrict__ nsum) {
    int idx = blockIdx.x * 256 + threadIdx.x;      // exactly 20000*512 threads
    int n = idx >> 9;
    int k = idx & 511;
    nsum[idx] = nodes[(size_t)n * 1024 + k] + nodes[(size_t)n * 1024 + 512 + k];
}

// ---------------- c[b,s] = 2 * dot(x[b,s,:], bp) ----------------
__global__ void cvec_kernel(const float* __restrict__ x, const float* __restrict__ bp,
                            float* __restrict__ c) {
    int row = blockIdx.x * 4 + (threadIdx.x >> 6);   // 512 rows
    int lane = threadIdx.x & 63;
    const float* xr = x + (size_t)row * 512;
    float s = 0.f;
    #pragma unroll
    for (int k = 0; k < 512; k += 64) s += xr[k + lane] * bp[k + lane];
    #pragma unroll
    for (int off = 32; off; off >>= 1) s += __shfl_down(s, off);
    if (lane == 0) c[row] = 2.0f * s;
}

// ---------------- degree count ----------------
__global__ void count_kernel(const int* __restrict__ dst, int* __restrict__ cnt, int E) {
    int e = blockIdx.x * 256 + threadIdx.x;
    if (e < E) atomicAdd(&cnt[dst[e]], 1);
}

__global__ void dinv_kernel(const int* __restrict__ cnt, float* __restrict__ dinv, int n) {
    int i = blockIdx.x * 256 + threadIdx.x;
    if (i < n) dinv[i] = rsqrtf((float)(cnt[i] + 1));   // +1 self loop
}

// ---------------- single-block exclusive scan (20000 ints) ----------------
__global__ __launch_bounds__(1024) void scan_kernel(const int* __restrict__ cnt,
                                                    int* __restrict__ offs, int n) {
    __shared__ int wsum[16];
    __shared__ int s_carry;
    int tid = threadIdx.x, lane = tid & 63, wid = tid >> 6;
    if (tid == 0) s_carry = 0;
    __syncthreads();
    for (int base = 0; base < n; base += 1024) {
        int i = base + tid;
        int v = (i < n) ? cnt[i] : 0;
        int x = v;
        #pragma unroll
        for (int off = 1; off < 64; off <<= 1) {
            int t = __shfl_up(x, off);
            if (lane >= off) x += t;
        }
        if (lane == 63) wsum[wid] = x;
        __syncthreads();
        if (wid == 0) {
            int wv = (lane < 16) ? wsum[lane] : 0;
            int wy = wv;
            #pragma unroll
            for (int off = 1; off < 16; off <<= 1) {
                int t = __shfl_up(wy, off);
                if (lane >= off) wy += t;
            }
            if (lane < 16) wsum[lane] = wy - wv;   // exclusive prefix of wave sums
        }
        __syncthreads();
        int excl = s_carry + wsum[wid] + x - v;
        if (i < n) offs[i] = excl;
        __syncthreads();
        if (tid == 1023) s_carry = excl + v;
        __syncthreads();
    }
    if (threadIdx.x == 0) offs[n] = s_carry;
}

// ---------------- CSR fill ----------------
__global__ void fill_kernel(const int* __restrict__ src, const int* __restrict__ dst,
                            const int* __restrict__ offs, int* __restrict__ cursor,
                            int* __restrict__ csr, int E) {
    int e = blockIdx.x * 256 + threadIdx.x;
    if (e < E) {
        int d = dst[e];
        int pos = atomicAdd(&cursor[d], 1);
        csr[offs[d] + pos] = src[e];
    }
}

// ---------------- y transpose: yT[b][j][s] = y[b*256+s][j] ----------------
__global__ void transpose_y(const float* __restrict__ y, float* __restrict__ yT) {
    int idx = blockIdx.x * 256 + threadIdx.x;  // 2*512*256 threads
    int s = idx & 255;
    int j = (idx >> 8) & 511;
    int b = idx >> 17;
    yT[idx] = y[((size_t)(b * 256 + s)) * 512 + j];
}

// ---------------- tiled fp32 GEMM: C[M,N] = A[M,K] @ B[K,N] (+colbias[n]) ----------------
__global__ __launch_bounds__(256) void gemm64(const float* __restrict__ A, const float* __restrict__ B,
                                              float* __restrict__ C, int M, int N, int K,
                                              const float* __restrict__ colbias) {
    __shared__ float As[16][68];   // [k][m], stride 68 keeps 16B align + 2-way banks
    __shared__ float Bs[16][64];   // [k][n]
    int bm = blockIdx.y * 64, bn = blockIdx.x * 64;
    int tid = threadIdx.x;
    int tx = tid & 15, ty = tid >> 4;
    int a_m = tid >> 2, a_k = (tid & 3) << 2;
    int b_k = tid >> 4, b_n = (tid & 15) << 2;
    float acc[4][4] = {};
    for (int k0 = 0; k0 < K; k0 += 16) {
        float4 av = make_float4(0.f, 0.f, 0.f, 0.f);
        if (bm + a_m < M) av = *(const float4*)(A + (size_t)(bm + a_m) * K + k0 + a_k);
        float4 bv = *(const float4*)(B + (size_t)(k0 + b_k) * N + bn + b_n);
        __syncthreads();
        As[a_k + 0][a_m] = av.x; As[a_k + 1][a_m] = av.y;
        As[a_k + 2][a_m] = av.z; As[a_k + 3][a_m] = av.w;
        *(float4*)&Bs[b_k][b_n] = bv;
        __syncthreads();
        #pragma unroll
        for (int kk = 0; kk < 16; ++kk) {
            float4 a = *(const float4*)&As[kk][ty << 2];
            float4 b = *(const float4*)&Bs[kk][tx << 2];
            float ar[4] = {a.x, a.y, a.z, a.w};
            float br[4] = {b.x, b.y, b.z, b.w};
            #pragma unroll
            for (int i = 0; i < 4; ++i)
                #pragma unroll
                for (int j = 0; j < 4; ++j) acc[i][j] += ar[i] * br[j];
        }
    }
    float cb[4] = {0.f, 0.f, 0.f, 0.f};
    if (colbias) {
        const float* p = colbias + bn + (tx << 2);
        cb[0] = p[0]; cb[1] = p[1]; cb[2] = p[2]; cb[3] = p[3];
    }
    #pragma unroll
    for (int i = 0; i < 4; ++i) {
        int row = bm + (ty << 2) + i;
        if (row < M) {
            float4 o;
            o.x = acc[i][0] + cb[0]; o.y = acc[i][1] + cb[1];
            o.z = acc[i][2] + cb[2]; o.w = acc[i][3] + cb[3];
            *(float4*)(C + (size_t)row * N + bn + (tx << 2)) = o;
        }
    }
}

// ---------------- GCN aggregation: one block per (node, b) ----------------
__global__ __launch_bounds__(256) void aggregate(const float* __restrict__ hw,
                                                 const int* __restrict__ offs,
                                                 const int* __restrict__ csr,
                                                 const float* __restrict__ dinv,
                                                 const float* __restrict__ bias,
                                                 float* __restrict__ hout, int N) {
    int n = blockIdx.x, b = blockIdx.y, s = threadIdx.x;
    const float* hwb = hw + (size_t)b * N * SDIM;
    float dn = dinv[n];
    float acc = dn * dn * hwb[(size_t)n * SDIM + s];       // self loop
    int e0 = offs[n], e1 = offs[n + 1];
    for (int e = e0; e < e1; ++e) {
        int src = csr[e];
        acc += dn * dinv[src] * hwb[(size_t)src * SDIM + s];
    }
    float v = acc + bias[s];
    hout[((size_t)b * N + n) * SDIM + s] = v > 0.f ? v : 0.01f * v;
}

// ---------------- final projection: out[b,n] = h[b,n,:]·w_bp + b_bp ----------------
__global__ void out_kernel(const float* __restrict__ h, const float* __restrict__ w_bp,
                           const float* __restrict__ b_bp, float* __restrict__ out) {
    int row = blockIdx.x * 4 + (threadIdx.x >> 6);   // 40000 rows
    int lane = threadIdx.x & 63;
    const float* hr = h + (size_t)row * SDIM;
    float s = 0.f;
    #pragma unroll
    for (int i = 0; i < 4; ++i) s += hr[i * 64 + lane] * w_bp[i * 64 + lane];
    #pragma unroll
    for (int off = 32; off; off >>= 1) s += __shfl_down(s, off);
    if (lane == 0) out[row] = s + b_bp[0];
}

extern "C" void kernel_launch(void* const* d_in, const int* in_sizes, int n_in,
                              void* d_out, int out_size, void* d_ws, size_t ws_size,
                              hipStream_t stream) {
    const float* x     = (const float*)d_in[0];
    const float* nodes = (const float*)d_in[1];
    const int*   eidx  = (const int*)d_in[2];
    const float* Wp    = (const float*)d_in[3];
    const float* bp    = (const float*)d_in[4];
    const float* gcn_W = (const float*)d_in[5];
    const float* gcn_b = (const float*)d_in[6];
    const float* w_bp  = (const float*)d_in[7];
    const float* b_bp  = (const float*)d_in[8];
    const int E = in_sizes[2] / 2;
    const int N = NNODES;

    char* w = (char*)d_ws;
    auto alloc = [&](size_t bytes) { char* p = w; w += (bytes + 255) & ~(size_t)255; return p; };
    float* nsum   = (float*)alloc((size_t)N * 512 * 4);      // 41 MB, reused as hw
    float* hA     = (float*)alloc((size_t)2 * N * 256 * 4);  // 41 MB
    float* hB     = (float*)alloc((size_t)2 * N * 256 * 4);  // 41 MB
    float* y      = (float*)alloc(512 * 512 * 4);
    float* yT     = (float*)alloc((size_t)2 * 512 * 256 * 4);
    float* cvec   = (float*)alloc(512 * 4);
    float* dinv   = (float*)alloc((size_t)N * 4);
    int*   cnt    = (int*)alloc((size_t)N * 4);
    int*   offs   = (int*)alloc((size_t)(N + 1) * 4);
    int*   cursor = (int*)alloc((size_t)N * 4);
    int*   csr    = (int*)alloc((size_t)E * 4);
    float* hw     = nsum;

    hipMemsetAsync(cnt, 0, (size_t)N * 4, stream);
    hipMemsetAsync(cursor, 0, (size_t)N * 4, stream);

    nsum_kernel<<<40000, 256, 0, stream>>>(nodes, nsum);
    gemm64<<<dim3(8, 8), 256, 0, stream>>>(x, Wp, y, 512, 512, 512, nullptr);
    transpose_y<<<1024, 256, 0, stream>>>(y, yT);
    cvec_kernel<<<128, 256, 0, stream>>>(x, bp, cvec);
    count_kernel<<<(E + 255) / 256, 256, 0, stream>>>(eidx + E, cnt, E);
    dinv_kernel<<<(N + 255) / 256, 256, 0, stream>>>(cnt, dinv, N);
    scan_kernel<<<1, 1024, 0, stream>>>(cnt, offs, N);
    fill_kernel<<<(E + 255) / 256, 256, 0, stream>>>(eidx, eidx + E, offs, cursor, csr, E);

    // h0[b,n,s] = nsum[n,:]·yT[b,:,s] + c[b,s]
    for (int b = 0; b < 2; ++b)
        gemm64<<<dim3(256 / 64, (N + 63) / 64), 256, 0, stream>>>(
            nsum, yT + (size_t)b * 512 * 256, hA + (size_t)b * N * 256,
            N, 256, 512, cvec + b * 256);

    float* hin = hA;
    float* hout = hB;
    for (int l = 0; l < 3; ++l) {
        gemm64<<<dim3(4, (2 * N) / 64), 256, 0, stream>>>(
            hin, gcn_W + (size_t)l * 256 * 256, hw, 2 * N, 256, 256, nullptr);
        aggregate<<<dim3(N, 2), 256, 0, stream>>>(hw, offs, csr, dinv, gcn_b + l * 256, hout, N);
        float* t = hin; hin = hout; hout = t;
    }
    out_kernel<<<10000, 256, 0, stream>>>(hin, w_bp, b_bp, (float*)d_out);
}